// Round 8
// baseline (245.416 us; speedup 1.0000x reference)
//
#include <hip/hip_runtime.h>

#define NN 16384   // total nodes (4*64*64)
#define CC 48      // channels
#define SPL 4      // j-stream splits

typedef __attribute__((ext_vector_type(8))) short bf16x8;
typedef __attribute__((ext_vector_type(4))) float f32x4;

__device__ __forceinline__ unsigned short f2bf(float f) {
  unsigned u = __float_as_uint(f);
  unsigned r = ((u >> 16) & 1u) + 0x7fffu;   // RNE
  return (unsigned short)((u + r) >> 16);
}
__device__ __forceinline__ float bf2f(unsigned short h) {
  return __uint_as_float(((unsigned)h) << 16);
}

// ---------- kernel 1: [B,C,H,W] -> xg[N][52] fp32, xh/xl[N][64] bf16 split, sqv[N] ----------
// Also zeroes deg[]; sqv[16383] = +inf (excludes the lone "batch 4" node as a
// candidate for batch-3 queries at zero hot-loop cost: dist = inf, never ranked).
__global__ __launch_bounds__(256) void prep_kernel(const float* __restrict__ x,
                                                   float* __restrict__ xg,
                                                   unsigned short* __restrict__ xh,
                                                   unsigned short* __restrict__ xl,
                                                   float* __restrict__ sqv,
                                                   int* __restrict__ deg) {
  __shared__ float tile[48][65];   // +1 pad
  __shared__ float sqcol[64];
  int tid = threadIdx.x;
  int b   = blockIdx.x >> 6;          // batch image 0..3
  int hw0 = (blockIdx.x & 63) << 6;   // 64-wide hw tile
  if (tid < 64) deg[blockIdx.x * 64 + tid] = 0;
#pragma unroll
  for (int p = 0; p < 12; ++p) {
    int it = tid + p * 256;
    int r = it >> 6, col = it & 63;
    tile[r][col] = x[(b * 48 + r) * 4096 + hw0 + col];
  }
  __syncthreads();
  if (tid < 64) {
    float s = 0.f;
#pragma unroll
    for (int r = 0; r < 48; ++r) { float v = tile[r][tid]; s += v * v; }
    sqcol[tid] = s;
    int node = b * 4096 + hw0 + tid;
    sqv[node] = (node == NN - 1) ? __builtin_inff() : s;
  }
  __syncthreads();
  float4* xg4 = (float4*)xg;
#pragma unroll
  for (int p = 0; p < 4; ++p) {
    int it = tid + p * 256;
    if (it < 832) {
      int col = it / 13;
      int q   = it - col * 13;
      float4 v;
      if (q < 12) {
        v.x = tile[q * 4 + 0][col]; v.y = tile[q * 4 + 1][col];
        v.z = tile[q * 4 + 2][col]; v.w = tile[q * 4 + 3][col];
      } else {
        v.x = sqcol[col]; v.y = 0.f; v.z = 0.f; v.w = 0.f;
      }
      xg4[(b * 4096 + hw0 + col) * 13 + q] = v;
    }
  }
  // bf16 hi/lo split, channels padded 48..63 with zeros
#pragma unroll
  for (int p = 0; p < 16; ++p) {
    int it = tid + p * 256;          // 4096 = 64 nodes x 64 ch
    int col = it >> 6, ch = it & 63;
    float v = (ch < 48) ? tile[ch][col] : 0.f;
    unsigned short h = f2bf(v);
    unsigned short l = f2bf(v - bf2f(h));
    size_t o = (size_t)(b * 4096 + hw0 + col) * 64 + ch;
    xh[o] = h;
    xl[o] = l;
  }
}

// ---------- kernel 2: MFMA distance + always-run exact f64 top-9 chain ----------
// Roles: A = candidates (streamed), B = queries (resident). Each lane owns ONE
// query (col) and 4 candidates/tile (rows quad*4+reg).
// Selection: NO accept test, NO LDS buffer, NO flush (the 64-lane __any tax
// made deferral flush nearly every tile — R7 post-mortem). Every candidate
// runs a fixed 9-step sorted-insert on q9[9] (ascending) via v_min_f64 /
// v_max_f64, 2 inst/step. Key = sortable_u32(dist)*256 + o, EXACT 40-bit
// integer in f64; o = t*4+reg is the lane-local ordinal, o-order == j-order
// within a lane so ties resolve to lower j exactly. q9 is hot every tile ->
// compiler keeps it in arch VGPRs (kills R7's AGPR ping-pong).
// dot = hi.hi' + hi.lo' + lo.hi' via 6 chained mfma_f32_16x16x32_bf16.
// End: f64 keys -> exact (k32, j) -> u64; 4 quad-partials merged in-wave.
__global__ __launch_bounds__(256, 4) void knn_kernel(const unsigned short* __restrict__ xh,
                                                     const unsigned short* __restrict__ xl,
                                                     const float* __restrict__ sqv,
                                                     unsigned long long* __restrict__ part) {
  __shared__ unsigned long long fin[4][64][9];   // 18.4 KB, final merge only
  int tid = threadIdx.x, wv = tid >> 6, lane = tid & 63;
  int wid = blockIdx.x * 4 + wv;
  int qt = wid & 1023, sp = wid >> 10;
  int col = lane & 15, quad = lane >> 4;
  int batch = qt >> 8;
  int js = batch * 4096 + sp * 1024;

  // resident B-frags (queries)
  int qnode = qt * 16 + col;
  bf16x8 bh0 = *(const bf16x8*)(xh + (size_t)qnode * 64 + quad * 8);
  bf16x8 bh1 = *(const bf16x8*)(xh + (size_t)qnode * 64 + 32 + quad * 8);
  bf16x8 bl0 = *(const bf16x8*)(xl + (size_t)qnode * 64 + quad * 8);
  bf16x8 bl1 = *(const bf16x8*)(xl + (size_t)qnode * 64 + 32 + quad * 8);

  double q9[9];
#pragma unroll
  for (int k = 0; k < 9; ++k) q9[k] = __builtin_inf();

  // prefetch tile 0: A-frags (candidate node js + col) + sq float4
  const unsigned short* pah = xh + ((size_t)(js + col) * 64 + quad * 8);
  const unsigned short* pal = xl + ((size_t)(js + col) * 64 + quad * 8);
  const float*          psq = sqv + (js + quad * 4);
  bf16x8 nh0 = *(const bf16x8*)(pah);
  bf16x8 nh1 = *(const bf16x8*)(pah + 32);
  bf16x8 nl0 = *(const bf16x8*)(pal);
  bf16x8 nl1 = *(const bf16x8*)(pal + 32);
  float4 nsq = *(const float4*)(psq);

  double od = 0.0;   // ordinal base = t*4 (exact integer in f64)
  for (int t = 0; t < 64; ++t) {
    bf16x8 ch0 = nh0, ch1 = nh1, cl0 = nl0, cl1 = nl1;
    float4 csq = nsq;
    int adv = (t < 63) ? 1024 : 0;       // 16 nodes * 64 ch
    pah += adv; pal += adv;
    nh0 = *(const bf16x8*)(pah);
    nh1 = *(const bf16x8*)(pah + 32);
    nl0 = *(const bf16x8*)(pal);
    nl1 = *(const bf16x8*)(pal + 32);
    psq += (t < 63) ? 16 : 0;
    nsq = *(const float4*)(psq);

    f32x4 acc = {0.f, 0.f, 0.f, 0.f};
    acc = __builtin_amdgcn_mfma_f32_16x16x32_bf16(ch0, bh0, acc, 0, 0, 0);  // hi.hi k0-31
    acc = __builtin_amdgcn_mfma_f32_16x16x32_bf16(ch1, bh1, acc, 0, 0, 0);  // hi.hi k32-63
    acc = __builtin_amdgcn_mfma_f32_16x16x32_bf16(ch0, bl0, acc, 0, 0, 0);  // hi.lo
    acc = __builtin_amdgcn_mfma_f32_16x16x32_bf16(ch1, bl1, acc, 0, 0, 0);
    acc = __builtin_amdgcn_mfma_f32_16x16x32_bf16(cl0, bh0, acc, 0, 0, 0);  // lo.hi
    acc = __builtin_amdgcn_mfma_f32_16x16x32_bf16(cl1, bh1, acc, 0, 0, 0);

    float sq4[4] = {csq.x, csq.y, csq.z, csq.w};
#pragma unroll
    for (int reg = 0; reg < 4; ++reg) {
      float d = fmaf(-2.f, acc[reg], sq4[reg]);   // key: sq_j - 2 dot (sq_i dropped)
      unsigned k32 = __float_as_uint(d);
      k32 = ((int)k32 >= 0) ? (k32 | 0x80000000u) : ~k32;   // sortable map
      double key = fma((double)k32, 256.0, od + (double)reg);  // exact 40-bit int
      double cu = key;
#pragma unroll
      for (int kk = 0; kk < 9; ++kk) {
        double mn = fmin(cu, q9[kk]);
        cu        = fmax(cu, q9[kk]);
        q9[kk]    = mn;
      }
    }
    od += 4.0;
  }

  // f64 keys -> exact (k32, o) -> j -> packed u64; stage for in-wave quad merge
  unsigned long long q9u[9];
#pragma unroll
  for (int k = 0; k < 9; ++k) {
    double d  = q9[k];
    double hi = floor(d * 0.00390625);     // d * 2^-8, exact
    double lo = d - hi * 256.0;            // ordinal o, exact
    unsigned k32 = (unsigned)hi;
    int o = (int)lo;
    int j = js + (o >> 2) * 16 + quad * 4 + (o & 3);
    q9u[k] = ((unsigned long long)k32 << 14) | (unsigned)j;
    fin[wv][lane][k] = q9u[k];
  }
  __threadfence_block();
  if (lane < 16) {
#pragma unroll
    for (int qd = 1; qd < 4; ++qd) {
      const unsigned long long* ob = fin[wv][qd * 16 + lane];
      for (int k = 0; k < 9; ++k) {
        unsigned long long key = ob[k];
        if (key >= q9u[8]) break;          // sorted ascending
        unsigned long long cu = key;
#pragma unroll
        for (int kk = 0; kk < 9; ++kk) {
          bool lt = cu < q9u[kk];
          unsigned long long mn = lt ? cu : q9u[kk];
          cu      = lt ? q9u[kk] : cu;
          q9u[kk] = mn;
        }
      }
    }
    int i = qt * 16 + lane;
#pragma unroll
    for (int k = 0; k < 9; ++k) part[(size_t)(k * SPL + sp) * NN + i] = q9u[k];
  }
}

// ---------- kernel 3: merge SPL sorted partial lists -> nbr, deg ----------
__global__ __launch_bounds__(64) void merge_kernel(const unsigned long long* __restrict__ part,
                                                   int* __restrict__ nbr,
                                                   int* __restrict__ deg) {
  int i = blockIdx.x * 64 + threadIdx.x;
  unsigned long long q9[9];
#pragma unroll
  for (int k = 0; k < 9; ++k) q9[k] = ~0ull;
  for (int s = 0; s < SPL; ++s) {
    for (int k = 0; k < 9; ++k) {
      unsigned long long key = part[(size_t)(k * SPL + s) * NN + i];
      if (key >= q9[8]) break;   // list k-sorted ascending
      unsigned long long cu = key;
#pragma unroll
      for (int m = 0; m < 9; ++m) {
        bool lt = cu < q9[m];
        unsigned long long mn = lt ? cu : q9[m];
        cu    = lt ? q9[m] : cu;
        q9[m] = mn;
      }
    }
  }
  int outi[9];
#pragma unroll
  for (int k = 0; k < 9; ++k) outi[k] = (int)(q9[k] & 0x3FFFull);
  // node 16383 sits alone in "batch 4": top_k over one valid entry + (-inf) ties
  // -> neighbors {16383, 0,1,...,7} (lowest-index tie-break). Matters for deg[0..7].
  if (i == NN - 1) {
    outi[0] = NN - 1;
#pragma unroll
    for (int k = 1; k < 9; ++k) outi[k] = k - 1;
  }
#pragma unroll
  for (int k = 0; k < 9; ++k) {
    nbr[i * 9 + k] = outi[k];
    atomicAdd(&deg[outi[k]], 1);
  }
}

// ---------- kernel 4: tx1 gather + out = relu(xf@W0 + tx1@W1 + b) ----------
__global__ __launch_bounds__(256) void out_kernel(const float* __restrict__ xg,
                                                  const int* __restrict__ nbr,
                                                  const int* __restrict__ deg,
                                                  const float* __restrict__ W0,
                                                  const float* __restrict__ W1,
                                                  const float* __restrict__ bias,
                                                  float* __restrict__ out) {
  __shared__ float w0s[48 * 48], w1s[48 * 48], bsh[48];
  __shared__ __align__(16) float xr[64 * 48];
  __shared__ float tx[64 * 48];
  __shared__ float wd[64][9];
  __shared__ int   jn[64][9];
  __shared__ float din[64];
  int tid = threadIdx.x;
  int r0  = blockIdx.x * 64;

  for (int p = tid; p < 2304; p += 256) { w0s[p] = W0[p]; w1s[p] = W1[p]; }
  if (tid < 48) bsh[tid] = bias[tid];
  if (tid < 64) {
    int d = deg[r0 + tid];
    din[tid] = d > 0 ? rsqrtf((float)d) : 0.0f;
  }
  const float4* xg4 = (const float4*)xg;
  float4* xr4 = (float4*)xr;
  for (int p = tid; p < 768; p += 256) {
    int r = p / 12, q = p - r * 12;
    xr4[r * 12 + q] = xg4[(r0 + r) * 13 + q];
  }
  for (int p = tid; p < 576; p += 256) {
    int r = p / 9, k = p - r * 9;
    int j = nbr[(r0 + r) * 9 + k];
    jn[r][k] = j;
    int d = deg[j];
    wd[r][k] = d > 0 ? rsqrtf((float)d) : 0.0f;
  }
  __syncthreads();

  for (int p = tid; p < 3072; p += 256) {
    int r = p / 48, ch = p - r * 48;
    float s = 0.f;
#pragma unroll
    for (int k = 0; k < 9; ++k) s += wd[r][k] * xg[jn[r][k] * 52 + ch];
    tx[r * 48 + ch] = -din[r] * s;
  }
  __syncthreads();

  for (int p = tid; p < 3072; p += 256) {
    int r = p / 48, o = p - r * 48;
    float acc = bsh[o];
#pragma unroll
    for (int cc = 0; cc < 48; ++cc)
      acc += xr[r * 48 + cc] * w0s[cc * 48 + o] + tx[r * 48 + cc] * w1s[cc * 48 + o];
    out[(r0 + r) * 48 + o] = fmaxf(acc, 0.f);
  }
}

extern "C" void kernel_launch(void* const* d_in, const int* in_sizes, int n_in,
                              void* d_out, int out_size, void* d_ws, size_t ws_size,
                              hipStream_t stream) {
  const float* x  = (const float*)d_in[0];
  const float* W0 = (const float*)d_in[1];
  const float* W1 = (const float*)d_in[2];
  const float* b  = (const float*)d_in[3];
  float* out = (float*)d_out;
  char* ws = (char*)d_ws;
  float*          xg   = (float*)(ws);                       // 3,407,872 B
  unsigned short* xh   = (unsigned short*)(ws + 3407872);    // 2,097,152 B
  unsigned short* xl   = (unsigned short*)(ws + 5505024);    // 2,097,152 B
  float*          sqv  = (float*)(ws + 7602176);             //    65,536 B
  int*            nbr  = (int*)(ws + 7667712);               //   589,824 B
  int*            deg  = (int*)(ws + 8257536);               //    65,536 B
  unsigned long long* part = (unsigned long long*)(ws + 8323072);  // 4,718,592 B

  prep_kernel<<<256, 256, 0, stream>>>(x, xg, xh, xl, sqv, deg);
  knn_kernel<<<1024, 256, 0, stream>>>(xh, xl, sqv, part);
  merge_kernel<<<256, 64, 0, stream>>>(part, nbr, deg);
  out_kernel<<<256, 256, 0, stream>>>(xg, nbr, deg, W0, W1, b, out);
}